// Round 3
// baseline (571.344 us; speedup 1.0000x reference)
//
#include <hip/hip_runtime.h>
#include <stdint.h>

#define AS1 __attribute__((address_space(1)))
#define AS3 __attribute__((address_space(3)))

typedef float floatx4 __attribute__((ext_vector_type(4)));
typedef __bf16 bf16x8 __attribute__((ext_vector_type(8)));

__device__ __forceinline__ unsigned short f2bf(float x) {
    union { float f; unsigned int u; } v; v.f = x;
    unsigned int r = v.u + 0x7fffu + ((v.u >> 16) & 1u);   // round-to-nearest-even
    return (unsigned short)(r >> 16);
}

// ---------------- fp32 -> bf16 bulk convert (vectorized, grid-stride) ----------------
__global__ __launch_bounds__(256) void cvt_bf16_kernel(
        const float* __restrict__ in, unsigned short* __restrict__ out, long n) {
    long i = ((long)blockIdx.x * blockDim.x + threadIdx.x) * 4;
    long stride = (long)gridDim.x * blockDim.x * 4;
    for (; i < n; i += stride) {
        float4 v = *(const float4*)(in + i);
        ushort4 o;
        o.x = f2bf(v.x); o.y = f2bf(v.y); o.z = f2bf(v.z); o.w = f2bf(v.w);
        *(ushort4*)(out + i) = o;
    }
}

// ---------------- weight_norm(dim=0): W[i,:] = g[i] * v[i,:] / ||v[i,:]|| -> bf16 ----------------
__global__ __launch_bounds__(256) void wn_kernel(
        const float* __restrict__ v, const float* __restrict__ g,
        unsigned short* __restrict__ W, int K) {
    int row = blockIdx.x;
    const float* vr = v + (size_t)row * K;
    float s = 0.f;
    for (int c = threadIdx.x; c < K; c += 256) { float x = vr[c]; s += x * x; }
    #pragma unroll
    for (int o = 32; o > 0; o >>= 1) s += __shfl_down(s, o, 64);
    __shared__ float red[4];
    __shared__ float scale_s;
    if ((threadIdx.x & 63) == 0) red[threadIdx.x >> 6] = s;
    __syncthreads();
    if (threadIdx.x == 0)
        scale_s = g[row] * rsqrtf(red[0] + red[1] + red[2] + red[3]);
    __syncthreads();
    float scale = scale_s;
    unsigned short* Wr = W + (size_t)row * K;
    for (int c = threadIdx.x; c < K; c += 256) Wr[c] = f2bf(vr[c] * scale);
}

// ---------------- NT GEMM: C[m,n] = sum_k A[m,k] * B[n,k] ----------------
// Restructured K-loop (v3):
//  - A tile: LDS double-buffered (2 x 16 KB), staged via global_load_lds(16B) with
//    XOR chunk swizzle (chunk g of row r at position g^(r&7)) -> conflict-free ds_read_b128.
//  - ONE barrier per iter: stage of tile k+1 issued after barrier k, drained by the
//    implicit vmcnt(0) at barrier k+1 (a whole MFMA phase later -> stall hidden).
//  - B fragments: loaded DIRECTLY from global (L2-resident panels), never touch LDS.
//    Lanes {l,l+16,l+32,l+48} cover one 64B line of a B row -> coalesced.
//  - CONCAT phase 2 (k>=2048): all 128 A rows == q[tileM>>9] -> A frag is one broadcast
//    16B load; NO LDS, NO barriers in phase 2.
template<int CONCAT, int RELU, int OUT_BF16>
__global__ __launch_bounds__(256) void gemm_bt_kernel(
        const unsigned short* __restrict__ A,
        const unsigned short* __restrict__ A2,   // q (bf16) when CONCAT
        const unsigned short* __restrict__ Bm,   // [Nd, K] row-major bf16
        const float* __restrict__ bias,
        void* __restrict__ Cout,
        int K, int ldc,
        long strideA, long strideB, long strideC) {
    const int t = threadIdx.x;
    const int bz = blockIdx.z;
    const int tileM = blockIdx.y * 128;
    const int tileN = blockIdx.x * 128;
    const unsigned short* Abase = A + (size_t)bz * strideA;
    const unsigned short* Bbase = Bm + (size_t)bz * strideB;

    __shared__ unsigned short As[2][128 * 64];   // double-buffered A tile

    const int lane = t & 63;
    const int wv = t >> 6;
    const int wm = (wv & 1) * 64;    // wave's 64x64 sub-tile
    const int wn = (wv >> 1) * 64;
    const int lr = lane & 15;        // MFMA fragment row (A: m, B: n)
    const int lk = (lane >> 4) * 8;  // un-swizzled fragment k element offset

    // swizzled intra-row element offsets for LDS A reads (ks = 0, 1)
    const int koff0 = (((lane >> 4) + 0) ^ (lane & 7)) * 8;
    const int koff1 = (((lane >> 4) + 4) ^ (lane & 7)) * 8;

    floatx4 acc[4][4];
    const floatx4 fzero = {0.f, 0.f, 0.f, 0.f};
    #pragma unroll
    for (int i = 0; i < 4; i++)
        #pragma unroll
        for (int j = 0; j < 4; j++) acc[i][j] = fzero;

    const int rowQ = t >> 3;                          // staging: row within 32-row pass
    const int colSw = ((t & 7) ^ (rowQ & 7)) * 8;     // staging: swizzled source chunk

    const int KA = CONCAT ? 2048 : K;   // A row length in phase 1
    const int n1 = KA / 64;

    // phase-1 A stage source pointers (advance +64 elems/iter)
    const unsigned short* aSrc[4];
    #pragma unroll
    for (int p = 0; p < 4; p++)
        aSrc[p] = Abase + (size_t)(tileM + p * 32 + rowQ) * KA + colSw;

    // B fragment pointers (advance +64 elems/iter)
    const unsigned short* bPtr[4];
    #pragma unroll
    for (int j = 0; j < 4; j++)
        bPtr[j] = Bbase + (size_t)(tileN + wn + j * 16 + lr) * K + lk;

    // prologue: stage tile 0 into As[0]
    #pragma unroll
    for (int p = 0; p < 4; p++)
        __builtin_amdgcn_global_load_lds((AS1 void*)aSrc[p],
                                         (AS3 void*)(&As[0][p * 2048 + t * 8]),
                                         16, 0, 0);

    for (int it = 0; it < n1; it++) {
        __syncthreads();   // per-wave vmcnt drain covers stage issued LAST iter (hidden)

        // current-tile B fragments, straight from L2
        bf16x8 bfr[2][4];
        #pragma unroll
        for (int ks = 0; ks < 2; ks++)
            #pragma unroll
            for (int j = 0; j < 4; j++)
                bfr[ks][j] = *(const bf16x8*)(bPtr[j] + ks * 32);

        // stage NEXT A tile into the other buffer (issued after B loads -> vmcnt layering)
        if (it + 1 < n1) {
            #pragma unroll
            for (int p = 0; p < 4; p++)
                __builtin_amdgcn_global_load_lds((AS1 void*)(aSrc[p] + 64),
                    (AS3 void*)(&As[(it + 1) & 1][p * 2048 + t * 8]), 16, 0, 0);
        }

        // compute from As[it&1]
        const unsigned short* asb = As[it & 1];
        #pragma unroll
        for (int ks = 0; ks < 2; ks++) {
            const int koff = ks ? koff1 : koff0;
            bf16x8 af[4];
            #pragma unroll
            for (int i = 0; i < 4; i++)
                af[i] = *(const bf16x8*)(&asb[(wm + i * 16 + lr) * 64 + koff]);
            #pragma unroll
            for (int i = 0; i < 4; i++)
                #pragma unroll
                for (int j = 0; j < 4; j++)
                    acc[i][j] = __builtin_amdgcn_mfma_f32_16x16x32_bf16(
                        af[i], bfr[ks][j], acc[i][j], 0, 0, 0);
        }
        #pragma unroll
        for (int p = 0; p < 4; p++) aSrc[p] += 64;
        #pragma unroll
        for (int j = 0; j < 4; j++) bPtr[j] += 64;
    }

    // phase 2 (CONCAT): k in [2048, 3072) -- every A row of the tile is q[b], b = tileM>>9.
    // No LDS, no barriers: broadcast q fragment + L2 B fragments + MFMA.
    if (CONCAT) {
        const unsigned short* qp = A2 + (size_t)(tileM >> 9) * 1024 + lk;
        #pragma unroll 4
        for (int it = 0; it < 16; it++) {
            bf16x8 bfr[2][4];
            #pragma unroll
            for (int ks = 0; ks < 2; ks++)
                #pragma unroll
                for (int j = 0; j < 4; j++)
                    bfr[ks][j] = *(const bf16x8*)(bPtr[j] + ks * 32);
            bf16x8 aq0 = *(const bf16x8*)(qp);
            bf16x8 aq1 = *(const bf16x8*)(qp + 32);
            #pragma unroll
            for (int ks = 0; ks < 2; ks++) {
                const bf16x8 aq = ks ? aq1 : aq0;
                #pragma unroll
                for (int i = 0; i < 4; i++)
                    #pragma unroll
                    for (int j = 0; j < 4; j++)
                        acc[i][j] = __builtin_amdgcn_mfma_f32_16x16x32_bf16(
                            aq, bfr[ks][j], acc[i][j], 0, 0, 0);
            }
            qp += 64;
            #pragma unroll
            for (int j = 0; j < 4; j++) bPtr[j] += 64;
        }
    }

    // epilogue: D row (M) = (lane>>4)*4 + r, col (N) = lane&15  [m89-verified layout]
    unsigned short* Cb = (unsigned short*)Cout + (size_t)bz * strideC;
    float* Cf = (float*)Cout + (size_t)bz * strideC;
    const int rowHalf = (lane >> 4) * 4;
    #pragma unroll
    for (int j = 0; j < 4; j++) {
        const int col = tileN + wn + j * 16 + lr;
        const float bv = RELU ? bias[col] : 0.0f;
        #pragma unroll
        for (int i = 0; i < 4; i++) {
            const int row0 = tileM + wm + i * 16 + rowHalf;
            #pragma unroll
            for (int r = 0; r < 4; r++) {
                float val = acc[i][j][r] + bv;
                if (RELU) val = fmaxf(val, 0.0f);
                const size_t off = (size_t)(row0 + r) * ldc + col;
                if (OUT_BF16) Cb[off] = f2bf(val);
                else          Cf[off] = val;
            }
        }
    }
}

// ---------------- gather: out[e] = S_flat[idx[e]] ----------------
__global__ __launch_bounds__(256) void gather_kernel(
        const float* __restrict__ S, const int* __restrict__ idx,
        float* __restrict__ out, int E) {
    int e = blockIdx.x * 256 + threadIdx.x;
    if (e < E) out[e] = S[idx[e]];
}

extern "C" void kernel_launch(void* const* d_in, const int* in_sizes, int n_in,
                              void* d_out, int out_size, void* d_ws, size_t ws_size,
                              hipStream_t stream) {
    const float* node = (const float*)d_in[0];   // [32,512,2048]
    const float* qf   = (const float*)d_in[1];   // [32,1024]
    const int*   idx  = (const int*)d_in[2];     // [1048576]
    const float* v1   = (const float*)d_in[3];   // [1024,3072]
    const float* g1   = (const float*)d_in[4];
    const float* b1   = (const float*)d_in[5];
    const float* v2   = (const float*)d_in[6];   // [1024,1024]
    const float* g2   = (const float*)d_in[7];
    const float* b2   = (const float*)d_in[8];
    float* out = (float*)d_out;

    // workspace carve (all offsets 256B aligned); S aliases nodesB (dead after GEMM1)
    char* ws = (char*)d_ws;
    unsigned short* W1     = (unsigned short*)(ws);              // 6,291,456 B
    unsigned short* W2     = (unsigned short*)(ws + 6291456);    // 2,097,152 B
    unsigned short* nodesB = (unsigned short*)(ws + 8388608);    // 67,108,864 B (reused as S)
    float*          S      = (float*)(ws + 8388608);             // 33,554,432 B (alias)
    unsigned short* qB     = (unsigned short*)(ws + 75497472);   // 65,536 B
    unsigned short* h1     = (unsigned short*)(ws + 75563008);   // 33,554,432 B
    unsigned short* h2     = (unsigned short*)(ws + 109117440);  // 33,554,432 B
    // total: 142,671,872 B

    // prep: bf16 conversions + weight-norm
    cvt_bf16_kernel<<<4096, 256, 0, stream>>>(node, nodesB, 33554432L);
    cvt_bf16_kernel<<<32,   256, 0, stream>>>(qf, qB, 32768L);
    wn_kernel<<<1024, 256, 0, stream>>>(v1, g1, W1, 3072);
    wn_kernel<<<1024, 256, 0, stream>>>(v2, g2, W2, 1024);

    dim3 blk(256);
    // h1 = relu(concat(nodes,q) @ W1^T + b1)   M=16384 N=1024 K=3072
    dim3 grid1(8, 128, 1);
    gemm_bt_kernel<1, 1, 1><<<grid1, blk, 0, stream>>>(
        nodesB, qB, W1, b1, h1, 3072, 1024, 0, 0, 0);
    // h2 = relu(h1 @ W2^T + b2)                M=16384 N=1024 K=1024
    gemm_bt_kernel<0, 1, 1><<<grid1, blk, 0, stream>>>(
        h1, nullptr, W2, b2, h2, 1024, 1024, 0, 0, 0);
    // S[b] = h2[b] @ h2[b]^T                   batched 512x512, K=1024, fp32 out
    dim3 gridg(4, 4, 32);
    gemm_bt_kernel<0, 0, 0><<<gridg, blk, 0, stream>>>(
        h2, nullptr, h2, nullptr, S, 1024, 512,
        512L * 1024L, 512L * 1024L, 512L * 512L);
    // gather
    gather_kernel<<<4096, 256, 0, stream>>>(S, idx, out, 1048576);
}

// Round 4
// 458.991 us; speedup vs baseline: 1.2448x; 1.2448x over previous
//
#include <hip/hip_runtime.h>
#include <stdint.h>

#define AS1 __attribute__((address_space(1)))
#define AS3 __attribute__((address_space(3)))

typedef float floatx4 __attribute__((ext_vector_type(4)));
typedef __bf16 bf16x8 __attribute__((ext_vector_type(8)));

__device__ __forceinline__ unsigned short f2bf(float x) {
    union { float f; unsigned int u; } v; v.f = x;
    unsigned int r = v.u + 0x7fffu + ((v.u >> 16) & 1u);   // round-to-nearest-even
    return (unsigned short)(r >> 16);
}

// ---------------- fp32 -> bf16 bulk convert (vectorized, grid-stride) ----------------
__global__ __launch_bounds__(256) void cvt_bf16_kernel(
        const float* __restrict__ in, unsigned short* __restrict__ out, long n) {
    long i = ((long)blockIdx.x * blockDim.x + threadIdx.x) * 4;
    long stride = (long)gridDim.x * blockDim.x * 4;
    for (; i < n; i += stride) {
        float4 v = *(const float4*)(in + i);
        ushort4 o;
        o.x = f2bf(v.x); o.y = f2bf(v.y); o.z = f2bf(v.z); o.w = f2bf(v.w);
        *(ushort4*)(out + i) = o;
    }
}

// ------- weight_norm(dim=0): W[i,:] = g[i]*v[i,:]/||v[i,:]|| -> bf16, scale -> fp32 -------
__global__ __launch_bounds__(256) void wn_kernel(
        const float* __restrict__ v, const float* __restrict__ g,
        unsigned short* __restrict__ W, float* __restrict__ scaleOut, int K) {
    int row = blockIdx.x;
    const float* vr = v + (size_t)row * K;
    float s = 0.f;
    for (int c = threadIdx.x; c < K; c += 256) { float x = vr[c]; s += x * x; }
    #pragma unroll
    for (int o = 32; o > 0; o >>= 1) s += __shfl_down(s, o, 64);
    __shared__ float red[4];
    __shared__ float scale_s;
    if ((threadIdx.x & 63) == 0) red[threadIdx.x >> 6] = s;
    __syncthreads();
    if (threadIdx.x == 0) {
        float sc = g[row] * rsqrtf(red[0] + red[1] + red[2] + red[3]);
        scale_s = sc;
        scaleOut[row] = sc;
    }
    __syncthreads();
    float scale = scale_s;
    unsigned short* Wr = W + (size_t)row * K;
    for (int c = threadIdx.x; c < K; c += 256) Wr[c] = f2bf(vr[c] * scale);
}

// ------- qh[b,d] = scale1[d] * sum_k qf[b,k] * v1[d, 2048+k]   (fp32, atomic partials) -------
// grid (dblk=8, ks=8), 256 threads. Each block: d in [dblk*128,+128), k in [ks*128,+128),
// all 32 b simultaneously (32 accumulators/thread, q slice staged in LDS).
__global__ __launch_bounds__(256) void qh_kernel(
        const float* __restrict__ qf, const float* __restrict__ v1,
        const float* __restrict__ scale1, float* __restrict__ qh) {
    const int t = threadIdx.x;
    const int dblk = blockIdx.x, ks = blockIdx.y;
    __shared__ float qs[32][128];
    for (int i = t; i < 4096; i += 256) {
        int b = i >> 7, kk = i & 127;
        qs[b][kk] = qf[b * 1024 + ks * 128 + kk];
    }
    __syncthreads();
    const int dLoc = t >> 1, khalf = t & 1;
    const int d = dblk * 128 + dLoc;
    const float* vp = v1 + (size_t)d * 3072 + 2048 + ks * 128 + khalf * 64;
    float acc[32];
    #pragma unroll
    for (int b = 0; b < 32; b++) acc[b] = 0.f;
    for (int j = 0; j < 64; j++) {
        float v = vp[j];
        const int kk = khalf * 64 + j;
        #pragma unroll
        for (int b = 0; b < 32; b++) acc[b] += v * qs[b][kk];
    }
    const float sc = scale1[d];
    #pragma unroll
    for (int b = 0; b < 32; b++) {
        float tot = acc[b] + __shfl_xor(acc[b], 1, 64);
        if (khalf == 0) atomicAdd(&qh[b * 1024 + d], sc * tot);
    }
}

// ---------------- NT GEMM: C[m,n] = sum_k A[m,k] * B[n,k]  (R2 structure) ----------------
// 128x128 tile, BK=64 bf16, 256 threads = 4 waves in 2x2, 16x16x32 MFMA, global_load_lds(16B).
// XOR chunk swizzle (chunk g of row r at LDS position g^(r&7)) -> conflict-free ds_read_b128.
// QH: adds block-uniform fp32 row bias qh[tileM>>9][col] in the epilogue (folded q@W1b^T).
template<int QH, int RELU, int OUT_BF16>
__global__ __launch_bounds__(256) void gemm_bt_kernel(
        const unsigned short* __restrict__ A,
        const unsigned short* __restrict__ Bm,   // [Nd, ldb] row-major bf16
        const float* __restrict__ bias,
        const float* __restrict__ qh,            // [32,1024] fp32 when QH
        void* __restrict__ Cout,
        int K, int lda, int ldb, int ldc,
        long strideA, long strideB, long strideC) {
    const int t = threadIdx.x;
    const int bz = blockIdx.z;
    const int tileM = blockIdx.y * 128;
    const int tileN = blockIdx.x * 128;
    const unsigned short* Abase = A + (size_t)bz * strideA;
    const unsigned short* Bbase = Bm + (size_t)bz * strideB;

    __shared__ unsigned short As[128 * 64];   // [row][64], contiguous for global_load_lds
    __shared__ unsigned short Bs[128 * 64];

    const int lane = t & 63;
    const int wv = t >> 6;
    const int wm = (wv & 1) * 64;    // wave's 64x64 sub-tile
    const int wn = (wv >> 1) * 64;
    const int lr = lane & 15;        // MFMA fragment row (A: m, B: n)

    // read-side swizzled intra-row element offsets (ks = 0, 1)
    const int koff0 = (((lane >> 4) + 0) ^ (lane & 7)) * 8;
    const int koff1 = (((lane >> 4) + 4) ^ (lane & 7)) * 8;

    floatx4 acc[4][4];
    const floatx4 fzero = {0.f, 0.f, 0.f, 0.f};
    #pragma unroll
    for (int i = 0; i < 4; i++)
        #pragma unroll
        for (int j = 0; j < 4; j++) acc[i][j] = fzero;

    const int rowQ = t >> 3;                          // 0..31: row within 32-row staging pass
    const int colSw = ((t & 7) ^ (rowQ & 7)) * 8;     // swizzled source chunk for this lane

    for (int k0 = 0; k0 < K; k0 += 64) {
        // stage A tile (128 rows x 64 bf16), 4 passes of 32 rows
        #pragma unroll
        for (int p = 0; p < 4; p++) {
            const int r = p * 32 + rowQ;
            const unsigned short* srcA = Abase + (size_t)(tileM + r) * lda + (k0 + colSw);
            __builtin_amdgcn_global_load_lds((AS1 void*)srcA,
                                             (AS3 void*)(&As[p * 2048 + t * 8]),
                                             16, 0, 0);
        }
        // stage B tile
        #pragma unroll
        for (int p = 0; p < 4; p++) {
            const int r = p * 32 + rowQ;
            const unsigned short* srcB = Bbase + (size_t)(tileN + r) * ldb + (k0 + colSw);
            __builtin_amdgcn_global_load_lds((AS1 void*)srcB,
                                             (AS3 void*)(&Bs[p * 2048 + t * 8]),
                                             16, 0, 0);
        }
        __syncthreads();   // drains vmcnt for global_load_lds per gfx950 barrier semantics

        #pragma unroll
        for (int ks = 0; ks < 2; ks++) {
            const int koff = ks ? koff1 : koff0;
            bf16x8 af[4], bfr[4];
            #pragma unroll
            for (int i = 0; i < 4; i++)
                af[i] = *(const bf16x8*)(&As[(wm + i * 16 + lr) * 64 + koff]);
            #pragma unroll
            for (int j = 0; j < 4; j++)
                bfr[j] = *(const bf16x8*)(&Bs[(wn + j * 16 + lr) * 64 + koff]);
            #pragma unroll
            for (int i = 0; i < 4; i++)
                #pragma unroll
                for (int j = 0; j < 4; j++)
                    acc[i][j] = __builtin_amdgcn_mfma_f32_16x16x32_bf16(
                        af[i], bfr[j], acc[i][j], 0, 0, 0);
        }
        __syncthreads();
    }

    // epilogue: D row (M) = (lane>>4)*4 + r, col (N) = lane&15  [m89-verified layout]
    unsigned short* Cb = (unsigned short*)Cout + (size_t)bz * strideC;
    float* Cf = (float*)Cout + (size_t)bz * strideC;
    const float* qhr = QH ? (qh + (size_t)(tileM >> 9) * 1024) : nullptr;
    const int rowHalf = (lane >> 4) * 4;
    #pragma unroll
    for (int j = 0; j < 4; j++) {
        const int col = tileN + wn + j * 16 + lr;
        float bv = RELU ? bias[col] : 0.0f;
        if (QH) bv += qhr[col];
        #pragma unroll
        for (int i = 0; i < 4; i++) {
            const int row0 = tileM + wm + i * 16 + rowHalf;
            #pragma unroll
            for (int r = 0; r < 4; r++) {
                float val = acc[i][j][r] + bv;
                if (RELU) val = fmaxf(val, 0.0f);
                const size_t off = (size_t)(row0 + r) * ldc + col;
                if (OUT_BF16) Cb[off] = f2bf(val);
                else          Cf[off] = val;
            }
        }
    }
}

// ---------------- gather: out[e] = S_flat[idx[e]] ----------------
__global__ __launch_bounds__(256) void gather_kernel(
        const float* __restrict__ S, const int* __restrict__ idx,
        float* __restrict__ out, int E) {
    int e = blockIdx.x * 256 + threadIdx.x;
    if (e < E) out[e] = S[idx[e]];
}

extern "C" void kernel_launch(void* const* d_in, const int* in_sizes, int n_in,
                              void* d_out, int out_size, void* d_ws, size_t ws_size,
                              hipStream_t stream) {
    const float* node = (const float*)d_in[0];   // [32,512,2048]
    const float* qf   = (const float*)d_in[1];   // [32,1024]
    const int*   idx  = (const int*)d_in[2];     // [1048576]
    const float* v1   = (const float*)d_in[3];   // [1024,3072]
    const float* g1   = (const float*)d_in[4];
    const float* b1   = (const float*)d_in[5];
    const float* v2   = (const float*)d_in[6];   // [1024,1024]
    const float* g2   = (const float*)d_in[7];
    const float* b2   = (const float*)d_in[8];
    float* out = (float*)d_out;

    // workspace carve (all offsets 256B aligned); S aliases nodesB (dead after GEMM1)
    char* ws = (char*)d_ws;
    unsigned short* W1     = (unsigned short*)(ws);              // 6,291,456 B
    unsigned short* W2     = (unsigned short*)(ws + 6291456);    // 2,097,152 B
    unsigned short* nodesB = (unsigned short*)(ws + 8388608);    // 67,108,864 B (reused as S)
    float*          S      = (float*)(ws + 8388608);             // 33,554,432 B (alias)
    unsigned short* h1     = (unsigned short*)(ws + 75563008);   // 33,554,432 B
    unsigned short* h2     = (unsigned short*)(ws + 109117440);  // 33,554,432 B
    float*          scale1 = (float*)(ws + 142671872);           // 4,096 B
    float*          scale2 = (float*)(ws + 142675968);           // 4,096 B
    float*          qh     = (float*)(ws + 142680064);           // 131,072 B
    // total: 142,811,136 B

    // prep: bf16 conversions + weight-norm + folded q@W1b^T
    cvt_bf16_kernel<<<4096, 256, 0, stream>>>(node, nodesB, 33554432L);
    wn_kernel<<<1024, 256, 0, stream>>>(v1, g1, W1, scale1, 3072);
    wn_kernel<<<1024, 256, 0, stream>>>(v2, g2, W2, scale2, 1024);
    hipMemsetAsync(qh, 0, 131072, stream);
    qh_kernel<<<dim3(8, 8), 256, 0, stream>>>(qf, v1, scale1, qh);

    dim3 blk(256);
    // h1 = relu(nodes @ W1a^T + qh[b] + b1)    M=16384 N=1024 K=2048 (ldb=3072)
    dim3 grid1(8, 128, 1);
    gemm_bt_kernel<1, 1, 1><<<grid1, blk, 0, stream>>>(
        nodesB, W1, b1, qh, h1, 2048, 2048, 3072, 1024, 0, 0, 0);
    // h2 = relu(h1 @ W2^T + b2)                M=16384 N=1024 K=1024
    gemm_bt_kernel<0, 1, 1><<<grid1, blk, 0, stream>>>(
        h1, W2, b2, nullptr, h2, 1024, 1024, 1024, 1024, 0, 0, 0);
    // S[b] = h2[b] @ h2[b]^T                   batched 512x512, K=1024, fp32 out
    dim3 gridg(4, 4, 32);
    gemm_bt_kernel<0, 0, 0><<<gridg, blk, 0, stream>>>(
        h2, h2, nullptr, nullptr, S, 1024, 1024, 1024, 512,
        512L * 1024L, 512L * 1024L, 512L * 512L);
    // gather
    gather_kernel<<<4096, 256, 0, stream>>>(S, idx, out, 1048576);
}